// Round 3
// baseline (522.382 us; speedup 1.0000x reference)
//
#include <hip/hip_runtime.h>

#define FEAT   64
#define NNEIGH 6
#define OUTF   64
#define INFEAT (NNEIGH * FEAT)   // 384

// ---------------------------------------------------------------------------
// Phase 1: Y[s, k*64 + o] = sum_f X[s, f] * W[o * 384 + k * 64 + f]
//
// Block = 256 threads = 4 waves, all over the SAME 64-site chunk.
// lane  = site within chunk (X row -> 64 VGPRs, reused 96x)
// wave q = output quarter: o in [q*16, q*16+16), all 6 k.
// All W indices are wave-uniform (q forced to SGPR via readfirstlane) ->
// compiler emits s_load for W; inner loop is v_fmac_f32 vacc, s_w, v_x.
// ---------------------------------------------------------------------------
__global__ __launch_bounds__(256) void lcnn_phase1(
    const float* __restrict__ X, const float* __restrict__ W,
    float* __restrict__ Y, int nsites) {
  const int lane = threadIdx.x & 63;
  const int q    = __builtin_amdgcn_readfirstlane(threadIdx.x >> 6);
  const int s    = blockIdx.x * 64 + lane;
  const bool valid = (s < nsites);
  const int  sl  = valid ? s : (nsites - 1);

  // X row (64 floats) into registers; clamped lanes read a duplicate row.
  float4 x[16];
  const float4* xp = (const float4*)(X + (size_t)sl * FEAT);
#pragma unroll
  for (int i = 0; i < 16; ++i) x[i] = xp[i];

  float* yrow = Y + (size_t)sl * INFEAT;

#pragma unroll 1
  for (int k = 0; k < NNEIGH; ++k) {
    const float* wk = W + k * FEAT;   // + o*INFEAT + f
    float*       yk = yrow + k * FEAT;
#pragma unroll 1
    for (int og = 0; og < 4; ++og) {
      const int o0 = q * 16 + og * 4;
      const float* w0 = wk + (size_t)(o0 + 0) * INFEAT;
      const float* w1 = wk + (size_t)(o0 + 1) * INFEAT;
      const float* w2 = wk + (size_t)(o0 + 2) * INFEAT;
      const float* w3 = wk + (size_t)(o0 + 3) * INFEAT;
      float a0 = 0.f, a1 = 0.f, a2 = 0.f, a3 = 0.f;
#pragma unroll
      for (int i = 0; i < 16; ++i) {
        float4 xv = x[i];
        a0 += xv.x * w0[4*i+0] + xv.y * w0[4*i+1] + xv.z * w0[4*i+2] + xv.w * w0[4*i+3];
        a1 += xv.x * w1[4*i+0] + xv.y * w1[4*i+1] + xv.z * w1[4*i+2] + xv.w * w1[4*i+3];
        a2 += xv.x * w2[4*i+0] + xv.y * w2[4*i+1] + xv.z * w2[4*i+2] + xv.w * w2[4*i+3];
        a3 += xv.x * w3[4*i+0] + xv.y * w3[4*i+1] + xv.z * w3[4*i+2] + xv.w * w3[4*i+3];
      }
      if (valid) *(float4*)(yk + o0) = make_float4(a0, a1, a2, a3);
    }
  }
}

// ---------------------------------------------------------------------------
// Phase 2: out[r, o] = b[o] + sum_k Y[idx[r,k] * 384 + k * 64 + o]
// Thread = (row, o4) with o4 a float4 chunk: every gather/store is a
// global_load_dwordx4 (1 KB per wave-instruction, coalesced 256 B segments).
// ---------------------------------------------------------------------------
__global__ __launch_bounds__(256) void lcnn_phase2(
    const int* __restrict__ idx, const float* __restrict__ Y,
    const float* __restrict__ b, float* __restrict__ out, int nrows) {
  const int tid = blockIdx.x * blockDim.x + threadIdx.x;
  const int total = nrows * 16;          // 16 float4 chunks per 64-float row
  if (tid >= total) return;
  const int row = tid >> 4;
  const int o4  = tid & 15;

  const int* ip = idx + (size_t)row * NNEIGH;
  const int s0 = ip[0], s1 = ip[1], s2 = ip[2], s3 = ip[3], s4 = ip[4], s5 = ip[5];

  const float4* Y4 = (const float4*)Y;   // INFEAT/4 = 96 float4 per site row
  float4 y0 = Y4[(size_t)s0 * 96 + 0 * 16 + o4];
  float4 y1 = Y4[(size_t)s1 * 96 + 1 * 16 + o4];
  float4 y2 = Y4[(size_t)s2 * 96 + 2 * 16 + o4];
  float4 y3 = Y4[(size_t)s3 * 96 + 3 * 16 + o4];
  float4 y4 = Y4[(size_t)s4 * 96 + 4 * 16 + o4];
  float4 y5 = Y4[(size_t)s5 * 96 + 5 * 16 + o4];
  float4 bb = ((const float4*)b)[o4];

  float4 r;
  r.x = bb.x + ((y0.x + y1.x) + (y2.x + y3.x)) + (y4.x + y5.x);
  r.y = bb.y + ((y0.y + y1.y) + (y2.y + y3.y)) + (y4.y + y5.y);
  r.z = bb.z + ((y0.z + y1.z) + (y2.z + y3.z)) + (y4.z + y5.z);
  r.w = bb.w + ((y0.w + y1.w) + (y2.w + y3.w)) + (y4.w + y5.w);

  ((float4*)out)[(size_t)row * 16 + o4] = r;
}

// ---------------------------------------------------------------------------
// Fallback (ws too small): direct 6x-FLOP computation, still correct.
// ---------------------------------------------------------------------------
__global__ __launch_bounds__(256) void lcnn_naive(
    const float* __restrict__ X, const int* __restrict__ idx,
    const float* __restrict__ W, const float* __restrict__ b,
    float* __restrict__ out, int nrows) {
  const int lane = threadIdx.x & 63;
  int row = blockIdx.x * 4 + (threadIdx.x >> 6);
  if (row >= nrows) return;

  const int* ip = idx + (size_t)row * NNEIGH;
  float acc = b[lane];
#pragma unroll 1
  for (int k = 0; k < NNEIGH; ++k) {
    const int s = ip[k];
    const float* xr = X + (size_t)s * FEAT;
    const float* wr = W + (size_t)lane * INFEAT + k * FEAT;
#pragma unroll
    for (int f = 0; f < FEAT; ++f) acc += xr[f] * wr[f];
  }
  out[(size_t)row * OUTF + lane] = acc;
}

extern "C" void kernel_launch(void* const* d_in, const int* in_sizes, int n_in,
                              void* d_out, int out_size, void* d_ws, size_t ws_size,
                              hipStream_t stream) {
  const float* X   = (const float*)d_in[0];
  const int*   idx = (const int*)d_in[1];
  // d_in[2] = N_sites scalar (unused)
  const float* W   = (const float*)d_in[3];
  const float* b   = (const float*)d_in[4];
  float*       out = (float*)d_out;

  const int nsites = in_sizes[0] / FEAT;      // 100000
  const int nrows  = in_sizes[1] / NNEIGH;    // 600000

  const size_t need = (size_t)nsites * INFEAT * sizeof(float);  // 153.6 MB
  if (ws_size >= need) {
    float* Y = (float*)d_ws;
    lcnn_phase1<<<(nsites + 63) / 64, 256, 0, stream>>>(X, W, Y, nsites);
    const int t2 = nrows * 16;
    lcnn_phase2<<<(t2 + 255) / 256, 256, 0, stream>>>(idx, Y, b, out, nrows);
  } else {
    lcnn_naive<<<(nrows + 3) / 4, 256, 0, stream>>>(X, idx, W, b, out, nrows);
  }
}